// Round 1
// baseline (150.723 us; speedup 1.0000x reference)
//
#include <hip/hip_runtime.h>
#include <math.h>

// SimpleSSM: u(B,DI,L) f32, A(S), B_mat(S,DI), C_mat(DO,S), D_mat(DO,DI), h0(S)
#define BZ 8
#define DI 256
#define DS 512
#define DOUT 256
#define LL 4096
#define BS (BZ * DS)   // 4096
#define CH 64
#define CT 64
#define TST 136        // k_bu scan-tile LDS stride in ushorts

typedef __bf16 bf16x8 __attribute__((ext_vector_type(8)));
typedef float f32x4 __attribute__((ext_vector_type(4)));
typedef unsigned short us8 __attribute__((ext_vector_type(8)));

// counted waitcnt (T4): n must be a literal
#define WAITV(n) asm volatile("s_waitcnt vmcnt(" #n ")" ::: "memory")
#define WAITL0   asm volatile("s_waitcnt lgkmcnt(0)" ::: "memory")

__device__ __forceinline__ ushort f2b(float f) {
    union { float f; unsigned u; } v; v.f = f;
    unsigned r = v.u + 0x7FFFu + ((v.u >> 16) & 1u);
    return (ushort)(r >> 16);
}
__device__ __forceinline__ float b2f(ushort h) {
    union { unsigned u; float f; } v; v.u = ((unsigned)h) << 16;
    return v.f;
}

__device__ __forceinline__ void gload16(const ushort* g, ushort* l) {
    __builtin_amdgcn_global_load_lds(
        (const __attribute__((address_space(1))) unsigned int*)g,
        (__attribute__((address_space(3))) unsigned int*)l,
        16, 0, 0);
}

// ---------------------------------------------------------------------------
// k_prep_u2t: blocks [0,2048): u transpose+bf16; blocks [2048,2368): apow +
// bf16 conversion of Bm/Cm/Dm + D!=0 flag.   (unchanged — ~BW-bound)
// ---------------------------------------------------------------------------
__global__ __launch_bounds__(256) void k_prep_u2t(const float* __restrict__ u,
                                                  ushort* __restrict__ utr,
                                                  const float* __restrict__ Au,
                                                  float* __restrict__ apow,
                                                  const float* __restrict__ Bm,
                                                  const float* __restrict__ Cm,
                                                  const float* __restrict__ Dm,
                                                  ushort* __restrict__ Bmb,
                                                  ushort* __restrict__ Cmb,
                                                  ushort* __restrict__ Dmb,
                                                  int* __restrict__ dflag) {
    __shared__ float T[64][65];
    const int tid = threadIdx.x;
    const int id = blockIdx.x;
    if (id < 2048) {   // ---- u2t role
        const int l0 = (id & 63) * 64;
        const int i0 = ((id >> 6) & 3) * 64;
        const int b  = id >> 8;
        const int r = tid >> 4, c4 = tid & 15;
#pragma unroll
        for (int rr = r; rr < 64; rr += 16) {
            float4 v = *(const float4*)&u[((size_t)b * DI + i0 + rr) * LL + l0 + c4 * 4];
            T[rr][c4 * 4 + 0] = v.x; T[rr][c4 * 4 + 1] = v.y;
            T[rr][c4 * 4 + 2] = v.z; T[rr][c4 * 4 + 3] = v.w;
        }
        __syncthreads();
#pragma unroll
        for (int ll = r; ll < 64; ll += 16) {
            ushort4 o;
            o.x = f2b(T[c4 * 4 + 0][ll]); o.y = f2b(T[c4 * 4 + 1][ll]);
            o.z = f2b(T[c4 * 4 + 2][ll]); o.w = f2b(T[c4 * 4 + 3][ll]);
            *(ushort4*)&utr[((size_t)b * LL + l0 + ll) * DI + i0 + c4 * 4] = o;
        }
    } else {           // ---- prep role
        const int t = (id - 2048) * 256 + tid;
        const int n1 = DS * DI / 4, n2 = DOUT * DS / 4, n3 = DOUT * DI / 4;
        if (t < n1) {
            float4 v = ((const float4*)Bm)[t];
            ushort4 o; o.x = f2b(v.x); o.y = f2b(v.y); o.z = f2b(v.z); o.w = f2b(v.w);
            ((ushort4*)Bmb)[t] = o;
        } else if (t < n1 + n2) {
            float4 v = ((const float4*)Cm)[t - n1];
            ushort4 o; o.x = f2b(v.x); o.y = f2b(v.y); o.z = f2b(v.z); o.w = f2b(v.w);
            ((ushort4*)Cmb)[t - n1] = o;
        } else if (t < n1 + n2 + n3) {
            float4 v = ((const float4*)Dm)[t - n1 - n2];
            ushort4 o; o.x = f2b(v.x); o.y = f2b(v.y); o.z = f2b(v.z); o.w = f2b(v.w);
            ((ushort4*)Dmb)[t - n1 - n2] = o;
            if (v.x != 0.f || v.y != 0.f || v.z != 0.f || v.w != 0.f)
                atomicOr(dflag, 1);
        }
        if (t < DS) {
            float x = Au[t];
            float sp = (x > 15.f) ? x : log1pf(expf(x));
            float ad = -sp;
            float p = 1.f;
            apow[t] = 1.f;
            for (int j = 1; j <= CT; ++j) { p *= ad; apow[j * DS + t] = p; }
        }
    }
}

// ---------------------------------------------------------------------------
// k_bu: Xb = local-scanned(B @ u) + finals.
// NEW: counted-vmcnt pipeline (T3/T4): raw s_barrier, A (Bmb, L2-hot)
// double-buffered 1 tile ahead, B (utr, HBM/L3) TRIPLE-buffered 2 ahead.
// vmcnt never drained to 0 in the steady-state loop.
// LDS (ushorts): A0=0, A1=4096 | B0=8192, B1=12288, B2=16384 (40 KB,
// 4 blocks/CU = 160 KB exactly); scan buffer overlays [0,17408).
// Per-wave vmcnt events: each stage = 2 gload16. Issue order per iter:
// A(it+1) then B(it+2). At top of iter it, pending <= {B(it),A(it),B(it+1)}
// -> WAITV(2) leaves only B(it+1): A(it),B(it) guaranteed landed.
// ---------------------------------------------------------------------------
__global__ __launch_bounds__(256) void k_bu(const ushort* __restrict__ Bmb,
                                            const ushort* __restrict__ utr,
                                            ushort* __restrict__ Xb,
                                            float* __restrict__ finals,
                                            const float* __restrict__ apow) {
    __shared__ ushort smem[20480];   // 40 KB
    const int tid = threadIdx.x;
    const int w = tid >> 6, lane = tid & 63;
    const int l0 = blockIdx.x * 128, s0 = blockIdx.y * 128, b = blockIdx.z;
    const int wm = w & 1, wn = w >> 1;
    const int mrow = lane & 15, quad = lane >> 4;
    const int sr = lane >> 2, sc = (lane & 3) * 8;
    const int off0 = (16 * w) * 32, off1 = (16 * w + 64) * 32;

    f32x4 acc[4][4];
#pragma unroll
    for (int mi = 0; mi < 4; ++mi)
#pragma unroll
        for (int ni = 0; ni < 4; ++ni) acc[mi][ni] = (f32x4)0.f;

    const ushort* ag0 = Bmb + (size_t)(s0 + 16 * w + sr) * DI + sc;
    const ushort* ag1 = ag0 + (size_t)64 * DI;
    const ushort* bg0 = utr + ((size_t)b * LL + l0 + 16 * w + sr) * DI + sc;
    const ushort* bg1 = bg0 + (size_t)64 * DI;

    // prologue: A(0)->A0, B(0)->B0, B(1)->B1   (6 loads outstanding)
    gload16(ag0, smem + off0);                 gload16(ag1, smem + off1);
    gload16(bg0, smem + 8192 + off0);          gload16(bg1, smem + 8192 + off1);
    gload16(bg0 + 32, smem + 12288 + off0);    gload16(bg1 + 32, smem + 12288 + off1);

#pragma unroll
    for (int it = 0; it < DI / 32; ++it) {
        if (it < 7) { WAITV(2); } else { WAITV(0); }
        __builtin_amdgcn_s_barrier();
        if (it + 1 < DI / 32) {   // A 1 ahead (L2-hot operand)
            const int kk = (it + 1) * 32, ab = ((it + 1) & 1) * 4096;
            gload16(ag0 + kk, smem + ab + off0); gload16(ag1 + kk, smem + ab + off1);
        }
        if (it + 2 < DI / 32) {   // B 2 ahead (HBM/L3 operand)
            const int kk = (it + 2) * 32, bb = 8192 + ((it + 2) % 3) * 4096;
            gload16(bg0 + kk, smem + bb + off0); gload16(bg1 + kk, smem + bb + off1);
        }
        const int ca = (it & 1) * 4096, cb = 8192 + (it % 3) * 4096;
        bf16x8 af[4], bfr[4];
#pragma unroll
        for (int mi = 0; mi < 4; ++mi)
            af[mi] = *(const bf16x8*)&smem[ca + (wm * 64 + mi * 16 + mrow) * 32 + quad * 8];
#pragma unroll
        for (int ni = 0; ni < 4; ++ni)
            bfr[ni] = *(const bf16x8*)&smem[cb + (wn * 64 + ni * 16 + mrow) * 32 + quad * 8];
#pragma unroll
        for (int mi = 0; mi < 4; ++mi)
#pragma unroll
            for (int ni = 0; ni < 4; ++ni)
                acc[mi][ni] = __builtin_amdgcn_mfma_f32_16x16x32_bf16(af[mi], bfr[ni], acc[mi][ni], 0, 0, 0);
    }
    __syncthreads();

#pragma unroll
    for (int mi = 0; mi < 4; ++mi) {
        const int sloc = wm * 64 + mi * 16 + quad * 4;
#pragma unroll
        for (int ni = 0; ni < 4; ++ni) {
            const int lloc = wn * 64 + ni * 16 + mrow;
            f32x4 v = acc[mi][ni];
            ushort4 o; o.x = f2b(v[0]); o.y = f2b(v[1]); o.z = f2b(v[2]); o.w = f2b(v[3]);
            *(ushort4*)&smem[lloc * TST + sloc] = o;
        }
    }
    __syncthreads();
    {
        const int cloc = tid >> 7, sl = tid & 127;
        const float a = apow[DS + s0 + sl];
        float acc2 = 0.f;
        ushort* p = &smem[(cloc * 64) * TST + sl];
#pragma unroll 8
        for (int j = 0; j < CT; ++j) {
            acc2 = a * acc2 + b2f(*p);
            *p = f2b(acc2);
            p += TST;
        }
        finals[(size_t)(l0 / 64 + cloc) * BS + (size_t)b * DS + s0 + sl] = acc2;
    }
    __syncthreads();
    {
        const int rr = tid >> 4, cc = tid & 15;
#pragma unroll
        for (int rep = 0; rep < 8; ++rep) {
            const int l = rep * 16 + rr;
            us8 v = *(const us8*)&smem[l * TST + cc * 8];
            *(us8*)&Xb[(size_t)(l0 + l) * BS + (size_t)b * DS + s0 + cc * 8] = v;
        }
    }
}

// ---------------------------------------------------------------------------
// k_out: Y = C @ (X + a^{j+1} carry) [+ D @ u if D != 0].
// NEW: (1) k_carry fused: each block redundantly computes its chunk's carry
// from finals (<=63 dependent FMAs, finals L2-hot) into a 2 KB LDS array
// during the prologue — chain hides under prologue load latency; one launch
// and the carries round-trip eliminated.
// (2) phase-1 counted-vmcnt pipeline: B (Cmb) triple-buffered 2 ahead via
// global_load_lds; X/apow register prefetch 2 iterations ahead (two statically
// indexed reg slots via full unroll). vmcnt events/iter: X=3 (xr,par,pbr),
// B-stage=2, issue order X then B. Top-of-iter pending <=
// {B(it):2, X(it+1):3, B(it+1):2} -> WAITV(5) guarantees B(it) landed.
// Compiler inserts exact vmcnt for the xr/par/pbr register uses in storeA.
// LDS (ushorts): A0=0, A1=2560 (stride 40); B0=5120, B1=9216, B2=13312;
// carry f32[512] @17408. Total 36.9 KB -> 4 blocks/CU.
// ---------------------------------------------------------------------------
__global__ __launch_bounds__(256) void k_out(const ushort* __restrict__ Cmb,
                                             const ushort* __restrict__ Dmb,
                                             const ushort* __restrict__ Xb,
                                             const ushort* __restrict__ utr,
                                             const float* __restrict__ finals,
                                             const float* __restrict__ apow,
                                             const float* __restrict__ h0,
                                             const int* __restrict__ dflag,
                                             float* __restrict__ Y) {
    __shared__ ushort smem[18432];   // 36.9 KB
    float* crl = (float*)&smem[17408];   // 512 f32, 16B-aligned
    const int tid = threadIdx.x;
    const int w = tid >> 6, lane = tid & 63;
    const int l0 = blockIdx.x * 64, o0 = blockIdx.y * 128, b = blockIdx.z;
    const int mrow = lane & 15, quad = lane >> 4;
    const int sr = lane >> 2, sc = (lane & 3) * 8;
    const int off0 = (16 * w) * 32, off1 = (16 * w + 64) * 32;
    const int dnz = *dflag;

    // ---- fused carry chain for this block's chunk c0 = blockIdx.x ----
    {
        const int c0 = blockIdx.x;
        const float aT0 = apow[CT * DS + tid];
        const float aT1 = apow[CT * DS + 256 + tid];
        float cva = h0[tid], cvb = h0[256 + tid];
        const float* fb = finals + (size_t)b * DS;
        for (int c = 0; c < c0; ++c) {
            cva = aT0 * cva + fb[(size_t)c * BS + tid];
            cvb = aT1 * cvb + fb[(size_t)c * BS + 256 + tid];
        }
        crl[tid] = cva; crl[256 + tid] = cvb;
    }
    __syncthreads();   // full drain: resets vmcnt/lgkm state before counted region

    f32x4 acc[4][2];
#pragma unroll
    for (int mi = 0; mi < 4; ++mi)
#pragma unroll
        for (int ni = 0; ni < 2; ++ni) acc[mi][ni] = (f32x4)0.f;

    auto compute = [&](const int aoff, const int ast, const int boff) {
        bf16x8 af[4], bfr[2];
#pragma unroll
        for (int mi = 0; mi < 4; ++mi)
            af[mi] = *(const bf16x8*)&smem[aoff + (mi * 16 + mrow) * ast + quad * 8];
#pragma unroll
        for (int ni = 0; ni < 2; ++ni)
            bfr[ni] = *(const bf16x8*)&smem[boff + (32 * w + ni * 16 + mrow) * 32 + quad * 8];
#pragma unroll
        for (int mi = 0; mi < 4; ++mi)
#pragma unroll
            for (int ni = 0; ni < 2; ++ni)
                acc[mi][ni] = __builtin_amdgcn_mfma_f32_16x16x32_bf16(af[mi], bfr[ni], acc[mi][ni], 0, 0, 0);
    };

    { // phase 1: C @ X_corrected, K = DS, 16 iters
        const int r0 = 16 * w + sr;              // 0..63 == chunk-local j
        const float* ap0 = &apow[(size_t)(r0 + 1) * DS];
        const ushort* x0 = Xb + (size_t)(l0 + r0) * BS + (size_t)b * DS;
        const ushort* bg0 = Cmb + (size_t)(o0 + r0) * DS + sc;
        const ushort* bg1 = bg0 + (size_t)64 * DS;

        // 2-deep register prefetch (slots statically indexed after unroll)
        us8 xr[2]; float4 par[2], pbr[2];
        auto loadX = [&](int it) {               // 3 vmcnt events
            const int sl = it & 1;
            const int col = it * 32 + sc;
            xr[sl]  = *(const us8*)&x0[col];
            par[sl] = *(const float4*)&ap0[col];
            pbr[sl] = *(const float4*)&ap0[col + 4];
        };
        auto storeA = [&](int it, int dstoff) {  // carries read from LDS at use
            const int sl = it & 1;
            const int col = it * 32 + sc;
            float4 c_a = *(const float4*)&crl[col];
            float4 c_b = *(const float4*)&crl[col + 4];
            us8 o;
            o[0] = f2b(b2f(xr[sl][0]) + par[sl].x * c_a.x);
            o[1] = f2b(b2f(xr[sl][1]) + par[sl].y * c_a.y);
            o[2] = f2b(b2f(xr[sl][2]) + par[sl].z * c_a.z);
            o[3] = f2b(b2f(xr[sl][3]) + par[sl].w * c_a.w);
            o[4] = f2b(b2f(xr[sl][4]) + pbr[sl].x * c_b.x);
            o[5] = f2b(b2f(xr[sl][5]) + pbr[sl].y * c_b.y);
            o[6] = f2b(b2f(xr[sl][6]) + pbr[sl].z * c_b.z);
            o[7] = f2b(b2f(xr[sl][7]) + pbr[sl].w * c_b.w);
            *(us8*)&smem[dstoff + r0 * 40 + sc] = o;
        };

        // prologue: X(0); B(0); B(1); X(1); storeA(0)
        loadX(0);
        gload16(bg0, smem + 5120 + off0);      gload16(bg1, smem + 5120 + off1);
        gload16(bg0 + 32, smem + 9216 + off0); gload16(bg1 + 32, smem + 9216 + off1);
        loadX(1);
        storeA(0, 0);      // compiler auto-waits exactly for X(0)
        WAITL0;

#pragma unroll
        for (int it = 0; it < DS / 32; ++it) {
            if (it < 15) { WAITV(5); } else { WAITV(0); }
            __builtin_amdgcn_s_barrier();
            if (it + 2 < DS / 32) {
                loadX(it + 2);                                   // 3 events
                const int kk = (it + 2) * 32, bb = 5120 + ((it + 2) % 3) * 4096;
                gload16(bg0 + kk, smem + bb + off0);             // 2 events
                gload16(bg1 + kk, smem + bb + off1);
            }
            compute((it & 1) * 2560, 40, 5120 + (it % 3) * 4096);
            if (it + 1 < DS / 32) {
                storeA(it + 1, ((it + 1) & 1) * 2560);
                WAITL0;    // publish ds_write before next barrier
            }
        }
    }
    if (dnz) { // phase 2: D @ u, K = DI, 8 iters (old-style loop; rare path)
        const ushort* ag0 = utr + ((size_t)b * LL + l0 + 16 * w + sr) * DI + sc;
        const ushort* bg0 = Dmb + (size_t)(o0 + 16 * w + sr) * DI + sc;
        const ushort* bg1 = bg0 + (size_t)64 * DI;

        __syncthreads();
        gload16(ag0, smem + off0);
        gload16(bg0, smem + 5120 + off0); gload16(bg1, smem + 5120 + off1);

        for (int it = 0; it < DI / 32; ++it) {
            __syncthreads();
            const int ca_ = (it & 1) * 2560, na_ = 2560 - ca_;
            const int cb_ = 5120 + (it & 1) * 4096, nb_ = 5120 + 4096 - (it & 1) * 4096;
            if (it + 1 < DI / 32) {
                const int kk = (it + 1) * 32;
                gload16(ag0 + kk, smem + na_ + off0);
                gload16(bg0 + kk, smem + nb_ + off0); gload16(bg1 + kk, smem + nb_ + off1);
            }
            compute(ca_, 32, cb_);
        }
    }

#pragma unroll
    for (int mi = 0; mi < 4; ++mi) {
        const int l = l0 + mi * 16 + quad * 4;
#pragma unroll
        for (int ni = 0; ni < 2; ++ni) {
            const int o = o0 + 32 * w + ni * 16 + mrow;
            *(float4*)&Y[((size_t)b * DOUT + o) * LL + l] = *(float4*)&acc[mi][ni];
        }
    }
}

// ---------------------------------------------------------------------------
extern "C" void kernel_launch(void* const* d_in, const int* in_sizes, int n_in,
                              void* d_out, int out_size, void* d_ws, size_t ws_size,
                              hipStream_t stream) {
    const float* u  = (const float*)d_in[0];
    const float* Au = (const float*)d_in[1];
    const float* Bm = (const float*)d_in[2];
    const float* Cm = (const float*)d_in[3];
    const float* Dm = (const float*)d_in[4];
    const float* h0 = (const float*)d_in[5];
    float* Y = (float*)d_out;

    char* p = (char*)d_ws;
    ushort* utr    = (ushort*)p; p += (size_t)BZ * LL * DI * 2;
    ushort* Xb     = (ushort*)p; p += (size_t)LL * BS * 2;
    float* finals  = (float*)p;  p += (size_t)CH * BS * 4;
    float* apow    = (float*)p;  p += (size_t)(CT + 1) * DS * 4;
    ushort* Bmb    = (ushort*)p; p += (size_t)DS * DI * 2;
    ushort* Cmb    = (ushort*)p; p += (size_t)DOUT * DS * 2;
    ushort* Dmb    = (ushort*)p; p += (size_t)DOUT * DI * 2;
    int* dflag     = (int*)p;    p += 16;

    hipMemsetAsync(dflag, 0, 4, stream);
    k_prep_u2t<<<dim3(2368), 256, 0, stream>>>(u, utr, Au, apow, Bm, Cm, Dm, Bmb, Cmb, Dmb, dflag);
    k_bu<<<dim3(LL / 128, DS / 128, BZ), 256, 0, stream>>>(Bmb, utr, Xb, finals, apow);
    k_out<<<dim3(LL / 64, DOUT / 128, BZ), 256, 0, stream>>>(Cmb, Dmb, Xb, utr, finals, apow, h0, dflag, Y);
}

// Round 2
// 143.590 us; speedup vs baseline: 1.0497x; 1.0497x over previous
//
#include <hip/hip_runtime.h>
#include <math.h>

// SimpleSSM: u(B,DI,L) f32, A(S), B_mat(S,DI), C_mat(DO,S), D_mat(DO,DI), h0(S)
#define BZ 8
#define DI 256
#define DS 512
#define DOUT 256
#define LL 4096
#define BS (BZ * DS)   // 4096
#define CH 64
#define CT 64
#define TST 136        // k_bu scan-tile LDS stride in ushorts

typedef __bf16 bf16x8 __attribute__((ext_vector_type(8)));
typedef float f32x4 __attribute__((ext_vector_type(4)));
typedef unsigned short us8 __attribute__((ext_vector_type(8)));

// counted waitcnt (T4): n must be a literal
#define WAITV(n) asm volatile("s_waitcnt vmcnt(" #n ")" ::: "memory")
#define WAITL0   asm volatile("s_waitcnt lgkmcnt(0)" ::: "memory")

__device__ __forceinline__ ushort f2b(float f) {
    union { float f; unsigned u; } v; v.f = f;
    unsigned r = v.u + 0x7FFFu + ((v.u >> 16) & 1u);
    return (ushort)(r >> 16);
}
__device__ __forceinline__ float b2f(ushort h) {
    union { unsigned u; float f; } v; v.u = ((unsigned)h) << 16;
    return v.f;
}

__device__ __forceinline__ void gload16(const ushort* g, ushort* l) {
    __builtin_amdgcn_global_load_lds(
        (const __attribute__((address_space(1))) unsigned int*)g,
        (__attribute__((address_space(3))) unsigned int*)l,
        16, 0, 0);
}

// ---------------------------------------------------------------------------
// k_prep_u2t: blocks [0,2048): u transpose+bf16; blocks [2048,2368): apow +
// bf16 conversion of Bm/Cm/Dm + D!=0 flag.   (unchanged)
// ---------------------------------------------------------------------------
__global__ __launch_bounds__(256) void k_prep_u2t(const float* __restrict__ u,
                                                  ushort* __restrict__ utr,
                                                  const float* __restrict__ Au,
                                                  float* __restrict__ apow,
                                                  const float* __restrict__ Bm,
                                                  const float* __restrict__ Cm,
                                                  const float* __restrict__ Dm,
                                                  ushort* __restrict__ Bmb,
                                                  ushort* __restrict__ Cmb,
                                                  ushort* __restrict__ Dmb,
                                                  int* __restrict__ dflag) {
    __shared__ float T[64][65];
    const int tid = threadIdx.x;
    const int id = blockIdx.x;
    if (id < 2048) {   // ---- u2t role
        const int l0 = (id & 63) * 64;
        const int i0 = ((id >> 6) & 3) * 64;
        const int b  = id >> 8;
        const int r = tid >> 4, c4 = tid & 15;
#pragma unroll
        for (int rr = r; rr < 64; rr += 16) {
            float4 v = *(const float4*)&u[((size_t)b * DI + i0 + rr) * LL + l0 + c4 * 4];
            T[rr][c4 * 4 + 0] = v.x; T[rr][c4 * 4 + 1] = v.y;
            T[rr][c4 * 4 + 2] = v.z; T[rr][c4 * 4 + 3] = v.w;
        }
        __syncthreads();
#pragma unroll
        for (int ll = r; ll < 64; ll += 16) {
            ushort4 o;
            o.x = f2b(T[c4 * 4 + 0][ll]); o.y = f2b(T[c4 * 4 + 1][ll]);
            o.z = f2b(T[c4 * 4 + 2][ll]); o.w = f2b(T[c4 * 4 + 3][ll]);
            *(ushort4*)&utr[((size_t)b * LL + l0 + ll) * DI + i0 + c4 * 4] = o;
        }
    } else {           // ---- prep role
        const int t = (id - 2048) * 256 + tid;
        const int n1 = DS * DI / 4, n2 = DOUT * DS / 4, n3 = DOUT * DI / 4;
        if (t < n1) {
            float4 v = ((const float4*)Bm)[t];
            ushort4 o; o.x = f2b(v.x); o.y = f2b(v.y); o.z = f2b(v.z); o.w = f2b(v.w);
            ((ushort4*)Bmb)[t] = o;
        } else if (t < n1 + n2) {
            float4 v = ((const float4*)Cm)[t - n1];
            ushort4 o; o.x = f2b(v.x); o.y = f2b(v.y); o.z = f2b(v.z); o.w = f2b(v.w);
            ((ushort4*)Cmb)[t - n1] = o;
        } else if (t < n1 + n2 + n3) {
            float4 v = ((const float4*)Dm)[t - n1 - n2];
            ushort4 o; o.x = f2b(v.x); o.y = f2b(v.y); o.z = f2b(v.z); o.w = f2b(v.w);
            ((ushort4*)Dmb)[t - n1 - n2] = o;
            if (v.x != 0.f || v.y != 0.f || v.z != 0.f || v.w != 0.f)
                atomicOr(dflag, 1);
        }
        if (t < DS) {
            float x = Au[t];
            float sp = (x > 15.f) ? x : log1pf(expf(x));
            float ad = -sp;
            float p = 1.f;
            apow[t] = 1.f;
            for (int j = 1; j <= CT; ++j) { p *= ad; apow[j * DS + t] = p; }
        }
    }
}

// ---------------------------------------------------------------------------
// k_bu: Xb = local-scanned(B @ u) + finals.  (unchanged from round 1)
// counted-vmcnt pipeline: A (Bmb, L2-hot) 2-buf 1-deep, B (utr) 3-buf 2-deep.
// ---------------------------------------------------------------------------
__global__ __launch_bounds__(256) void k_bu(const ushort* __restrict__ Bmb,
                                            const ushort* __restrict__ utr,
                                            ushort* __restrict__ Xb,
                                            float* __restrict__ finals,
                                            const float* __restrict__ apow) {
    __shared__ ushort smem[20480];   // 40 KB
    const int tid = threadIdx.x;
    const int w = tid >> 6, lane = tid & 63;
    const int l0 = blockIdx.x * 128, s0 = blockIdx.y * 128, b = blockIdx.z;
    const int wm = w & 1, wn = w >> 1;
    const int mrow = lane & 15, quad = lane >> 4;
    const int sr = lane >> 2, sc = (lane & 3) * 8;
    const int off0 = (16 * w) * 32, off1 = (16 * w + 64) * 32;

    f32x4 acc[4][4];
#pragma unroll
    for (int mi = 0; mi < 4; ++mi)
#pragma unroll
        for (int ni = 0; ni < 4; ++ni) acc[mi][ni] = (f32x4)0.f;

    const ushort* ag0 = Bmb + (size_t)(s0 + 16 * w + sr) * DI + sc;
    const ushort* ag1 = ag0 + (size_t)64 * DI;
    const ushort* bg0 = utr + ((size_t)b * LL + l0 + 16 * w + sr) * DI + sc;
    const ushort* bg1 = bg0 + (size_t)64 * DI;

    // prologue: A(0)->A0, B(0)->B0, B(1)->B1   (6 loads outstanding)
    gload16(ag0, smem + off0);                 gload16(ag1, smem + off1);
    gload16(bg0, smem + 8192 + off0);          gload16(bg1, smem + 8192 + off1);
    gload16(bg0 + 32, smem + 12288 + off0);    gload16(bg1 + 32, smem + 12288 + off1);

#pragma unroll
    for (int it = 0; it < DI / 32; ++it) {
        if (it < 7) { WAITV(2); } else { WAITV(0); }
        __builtin_amdgcn_s_barrier();
        if (it + 1 < DI / 32) {   // A 1 ahead (L2-hot operand)
            const int kk = (it + 1) * 32, ab = ((it + 1) & 1) * 4096;
            gload16(ag0 + kk, smem + ab + off0); gload16(ag1 + kk, smem + ab + off1);
        }
        if (it + 2 < DI / 32) {   // B 2 ahead (HBM/L3 operand)
            const int kk = (it + 2) * 32, bb = 8192 + ((it + 2) % 3) * 4096;
            gload16(bg0 + kk, smem + bb + off0); gload16(bg1 + kk, smem + bb + off1);
        }
        const int ca = (it & 1) * 4096, cb = 8192 + (it % 3) * 4096;
        bf16x8 af[4], bfr[4];
#pragma unroll
        for (int mi = 0; mi < 4; ++mi)
            af[mi] = *(const bf16x8*)&smem[ca + (wm * 64 + mi * 16 + mrow) * 32 + quad * 8];
#pragma unroll
        for (int ni = 0; ni < 4; ++ni)
            bfr[ni] = *(const bf16x8*)&smem[cb + (wn * 64 + ni * 16 + mrow) * 32 + quad * 8];
#pragma unroll
        for (int mi = 0; mi < 4; ++mi)
#pragma unroll
            for (int ni = 0; ni < 4; ++ni)
                acc[mi][ni] = __builtin_amdgcn_mfma_f32_16x16x32_bf16(af[mi], bfr[ni], acc[mi][ni], 0, 0, 0);
    }
    __syncthreads();

#pragma unroll
    for (int mi = 0; mi < 4; ++mi) {
        const int sloc = wm * 64 + mi * 16 + quad * 4;
#pragma unroll
        for (int ni = 0; ni < 4; ++ni) {
            const int lloc = wn * 64 + ni * 16 + mrow;
            f32x4 v = acc[mi][ni];
            ushort4 o; o.x = f2b(v[0]); o.y = f2b(v[1]); o.z = f2b(v[2]); o.w = f2b(v[3]);
            *(ushort4*)&smem[lloc * TST + sloc] = o;
        }
    }
    __syncthreads();
    {
        const int cloc = tid >> 7, sl = tid & 127;
        const float a = apow[DS + s0 + sl];
        float acc2 = 0.f;
        ushort* p = &smem[(cloc * 64) * TST + sl];
#pragma unroll 8
        for (int j = 0; j < CT; ++j) {
            acc2 = a * acc2 + b2f(*p);
            *p = f2b(acc2);
            p += TST;
        }
        finals[(size_t)(l0 / 64 + cloc) * BS + (size_t)b * DS + s0 + sl] = acc2;
    }
    __syncthreads();
    {
        const int rr = tid >> 4, cc = tid & 15;
#pragma unroll
        for (int rep = 0; rep < 8; ++rep) {
            const int l = rep * 16 + rr;
            us8 v = *(const us8*)&smem[l * TST + cc * 8];
            *(us8*)&Xb[(size_t)(l0 + l) * BS + (size_t)b * DS + s0 + cc * 8] = v;
        }
    }
}

// ---------------------------------------------------------------------------
// k_out: Y = C @ (X + a^{j+1} carry) [+ D @ u if D != 0].
// Round-2 changes (k_out only):
//  (1) carry chain de-serialized: finals loads batched 8-at-a-time into
//      statically-indexed registers -> one L3 latency per 8 steps, not per
//      step (worst block ~16us -> ~2us). FMA order identical (bitwise same).
//  (2) phase-1 prefetches (X(0..2), B(0), B(1)) issued BEFORE the carry
//      chain; the crl-publishing __syncthreads drains them -> loop enters
//      fully warm.
//  (3) X register prefetch deepened to 3 slots (it%3, static after unroll):
//      storeA's X has 2 iterations + compute of latency cover.
// WAITV derivation: WAITV sits before any of iter it's own issues, so
// "<=N outstanding" forces everything issued through iter it-2 regardless of
// intra-iteration reordering. Steady: iter j issues X(j+3):3 + B(j+2):2 = 5
// -> WAITV(5) forces B(it) (+X(it+1)). Tail: it==14 -> WAITV(2) (only B15
// newer than B14's iteration), it==15 -> WAITV(0).
// LDS (ushorts): A0=0, A1=2560 (stride 40); B0=5120, B1=9216, B2=13312;
// carry f32[512] @17408. Total 36.9 KB -> 4 blocks/CU.
// ---------------------------------------------------------------------------
__global__ __launch_bounds__(256) void k_out(const ushort* __restrict__ Cmb,
                                             const ushort* __restrict__ Dmb,
                                             const ushort* __restrict__ Xb,
                                             const ushort* __restrict__ utr,
                                             const float* __restrict__ finals,
                                             const float* __restrict__ apow,
                                             const float* __restrict__ h0,
                                             const int* __restrict__ dflag,
                                             float* __restrict__ Y) {
    __shared__ ushort smem[18432];   // 36.9 KB
    float* crl = (float*)&smem[17408];   // 512 f32
    const int tid = threadIdx.x;
    const int w = tid >> 6, lane = tid & 63;
    const int l0 = blockIdx.x * 64, o0 = blockIdx.y * 128, b = blockIdx.z;
    const int mrow = lane & 15, quad = lane >> 4;
    const int sr = lane >> 2, sc = (lane & 3) * 8;
    const int off0 = (16 * w) * 32, off1 = (16 * w + 64) * 32;
    const int dnz = *dflag;

    f32x4 acc[4][2];
#pragma unroll
    for (int mi = 0; mi < 4; ++mi)
#pragma unroll
        for (int ni = 0; ni < 2; ++ni) acc[mi][ni] = (f32x4)0.f;

    auto compute = [&](const int aoff, const int ast, const int boff) {
        bf16x8 af[4], bfr[2];
#pragma unroll
        for (int mi = 0; mi < 4; ++mi)
            af[mi] = *(const bf16x8*)&smem[aoff + (mi * 16 + mrow) * ast + quad * 8];
#pragma unroll
        for (int ni = 0; ni < 2; ++ni)
            bfr[ni] = *(const bf16x8*)&smem[boff + (32 * w + ni * 16 + mrow) * 32 + quad * 8];
#pragma unroll
        for (int mi = 0; mi < 4; ++mi)
#pragma unroll
            for (int ni = 0; ni < 2; ++ni)
                acc[mi][ni] = __builtin_amdgcn_mfma_f32_16x16x32_bf16(af[mi], bfr[ni], acc[mi][ni], 0, 0, 0);
    };

    { // phase 1: C @ X_corrected, K = DS, 16 iters
        const int r0 = 16 * w + sr;              // 0..63 == chunk-local j
        const float* ap0 = &apow[(size_t)(r0 + 1) * DS];
        const ushort* x0 = Xb + (size_t)(l0 + r0) * BS + (size_t)b * DS;
        const ushort* bg0 = Cmb + (size_t)(o0 + r0) * DS + sc;
        const ushort* bg1 = bg0 + (size_t)64 * DS;

        // 3-deep register prefetch (slots static after full unroll)
        us8 xr[3]; float4 par[3], pbr[3];
        auto loadX = [&](int it) {               // 3 vmcnt events
            const int sl = it % 3;
            const int col = it * 32 + sc;
            xr[sl]  = *(const us8*)&x0[col];
            par[sl] = *(const float4*)&ap0[col];
            pbr[sl] = *(const float4*)&ap0[col + 4];
        };
        auto storeA = [&](int it, int dstoff) {
            const int sl = it % 3;
            const int col = it * 32 + sc;
            float4 c_a = *(const float4*)&crl[col];
            float4 c_b = *(const float4*)&crl[col + 4];
            us8 o;
            o[0] = f2b(b2f(xr[sl][0]) + par[sl].x * c_a.x);
            o[1] = f2b(b2f(xr[sl][1]) + par[sl].y * c_a.y);
            o[2] = f2b(b2f(xr[sl][2]) + par[sl].z * c_a.z);
            o[3] = f2b(b2f(xr[sl][3]) + par[sl].w * c_a.w);
            o[4] = f2b(b2f(xr[sl][4]) + pbr[sl].x * c_b.x);
            o[5] = f2b(b2f(xr[sl][5]) + pbr[sl].y * c_b.y);
            o[6] = f2b(b2f(xr[sl][6]) + pbr[sl].z * c_b.z);
            o[7] = f2b(b2f(xr[sl][7]) + pbr[sl].w * c_b.w);
            *(us8*)&smem[dstoff + r0 * 40 + sc] = o;
        };

        // ---- issue all prologue prefetches FIRST (complete during carry) ----
        loadX(0); loadX(1); loadX(2);
        gload16(bg0, smem + 5120 + off0);      gload16(bg1, smem + 5120 + off1);
        gload16(bg0 + 32, smem + 9216 + off0); gload16(bg1 + 32, smem + 9216 + off1);

        // ---- fused carry chain, loads batched by 8 (overlaps the above) ----
        {
            const int c0 = blockIdx.x;           // == this block's chunk
            const float aT0 = apow[CT * DS + tid];
            const float aT1 = apow[CT * DS + 256 + tid];
            float cva = h0[tid], cvb = h0[256 + tid];
            const float* fb = finals + (size_t)b * DS;
            int c = 0;
            for (; c + 8 <= c0; c += 8) {
                float fa[8], fc[8];
#pragma unroll
                for (int j = 0; j < 8; ++j) {
                    fa[j] = fb[(size_t)(c + j) * BS + tid];
                    fc[j] = fb[(size_t)(c + j) * BS + 256 + tid];
                }
#pragma unroll
                for (int j = 0; j < 8; ++j) {
                    cva = aT0 * cva + fa[j];
                    cvb = aT1 * cvb + fc[j];
                }
            }
            for (; c < c0; ++c) {
                cva = aT0 * cva + fb[(size_t)c * BS + tid];
                cvb = aT1 * cvb + fb[(size_t)c * BS + 256 + tid];
            }
            crl[tid] = cva; crl[256 + tid] = cvb;
        }
        __syncthreads();   // publish crl; drains all prologue loads (warm entry)

        storeA(0, 0);
        WAITL0;

#pragma unroll
        for (int it = 0; it < DS / 32; ++it) {
            if (it < 14) { WAITV(5); } else if (it == 14) { WAITV(2); } else { WAITV(0); }
            __builtin_amdgcn_s_barrier();
            if (it + 3 < DS / 32) loadX(it + 3);                 // 3 events
            if (it + 2 < DS / 32) {
                const int kk = (it + 2) * 32, bb = 5120 + ((it + 2) % 3) * 4096;
                gload16(bg0 + kk, smem + bb + off0);             // 2 events
                gload16(bg1 + kk, smem + bb + off1);
            }
            compute((it & 1) * 2560, 40, 5120 + (it % 3) * 4096);
            if (it + 1 < DS / 32) {
                storeA(it + 1, ((it + 1) & 1) * 2560);
                WAITL0;    // publish ds_write before next barrier
            }
        }
    }
    if (dnz) { // phase 2: D @ u, K = DI, 8 iters (rare path; D==0 skips)
        const ushort* ag0 = utr + ((size_t)b * LL + l0 + 16 * w + sr) * DI + sc;
        const ushort* bg0 = Dmb + (size_t)(o0 + 16 * w + sr) * DI + sc;
        const ushort* bg1 = bg0 + (size_t)64 * DI;

        __syncthreads();
        gload16(ag0, smem + off0);
        gload16(bg0, smem + 5120 + off0); gload16(bg1, smem + 5120 + off1);

        for (int it = 0; it < DI / 32; ++it) {
            __syncthreads();
            const int ca_ = (it & 1) * 2560, na_ = 2560 - ca_;
            const int cb_ = 5120 + (it & 1) * 4096, nb_ = 5120 + 4096 - (it & 1) * 4096;
            if (it + 1 < DI / 32) {
                const int kk = (it + 1) * 32;
                gload16(ag0 + kk, smem + na_ + off0);
                gload16(bg0 + kk, smem + nb_ + off0); gload16(bg1 + kk, smem + nb_ + off1);
            }
            compute(ca_, 32, cb_);
        }
    }

#pragma unroll
    for (int mi = 0; mi < 4; ++mi) {
        const int l = l0 + mi * 16 + quad * 4;
#pragma unroll
        for (int ni = 0; ni < 2; ++ni) {
            const int o = o0 + 32 * w + ni * 16 + mrow;
            *(float4*)&Y[((size_t)b * DOUT + o) * LL + l] = *(float4*)&acc[mi][ni];
        }
    }
}

// ---------------------------------------------------------------------------
extern "C" void kernel_launch(void* const* d_in, const int* in_sizes, int n_in,
                              void* d_out, int out_size, void* d_ws, size_t ws_size,
                              hipStream_t stream) {
    const float* u  = (const float*)d_in[0];
    const float* Au = (const float*)d_in[1];
    const float* Bm = (const float*)d_in[2];
    const float* Cm = (const float*)d_in[3];
    const float* Dm = (const float*)d_in[4];
    const float* h0 = (const float*)d_in[5];
    float* Y = (float*)d_out;

    char* p = (char*)d_ws;
    ushort* utr    = (ushort*)p; p += (size_t)BZ * LL * DI * 2;
    ushort* Xb     = (ushort*)p; p += (size_t)LL * BS * 2;
    float* finals  = (float*)p;  p += (size_t)CH * BS * 4;
    float* apow    = (float*)p;  p += (size_t)(CT + 1) * DS * 4;
    ushort* Bmb    = (ushort*)p; p += (size_t)DS * DI * 2;
    ushort* Cmb    = (ushort*)p; p += (size_t)DOUT * DS * 2;
    ushort* Dmb    = (ushort*)p; p += (size_t)DOUT * DI * 2;
    int* dflag     = (int*)p;    p += 16;

    hipMemsetAsync(dflag, 0, 4, stream);
    k_prep_u2t<<<dim3(2368), 256, 0, stream>>>(u, utr, Au, apow, Bm, Cm, Dm, Bmb, Cmb, Dmb, dflag);
    k_bu<<<dim3(LL / 128, DS / 128, BZ), 256, 0, stream>>>(Bmb, utr, Xb, finals, apow);
    k_out<<<dim3(LL / 64, DOUT / 128, BZ), 256, 0, stream>>>(Cmb, Dmb, Xb, utr, finals, apow, h0, dflag, Y);
}